// Round 7
// baseline (119.854 us; speedup 1.0000x reference)
//
#include <hip/hip_runtime.h>
#include <math.h>

#define EPSF 1e-8f

typedef __attribute__((ext_vector_type(4))) short short4v;
typedef __attribute__((ext_vector_type(8))) short short8v;
typedef __attribute__((ext_vector_type(4))) float float4v;

__device__ inline short f2bf(float f) {
    unsigned u = __builtin_bit_cast(unsigned, f);
    unsigned r = (u + 0x7FFFu + ((u >> 16) & 1u)) >> 16;
    return (short)r;
}

// F layout (bf16 shorts): f1t @0 (4*128*4096), f1s @2097152, f2t @4194304
// (4*256*1024), f2s @5242880; total 6291456 shorts = 12.6 MB.
#define F1T 0
#define F1S 2097152
#define F2T 4194304
#define F2S 5242880

// Sub-tile combos {g, ri, rj, w}; tile unit = 64 rows. g: 0=t*t 1=s*s 2=t*s.
// Diagonal grams symmetric: upper triangle; diag tile w=1, off-diag w=2
// (internal square of a diagonal tile is exact); cross gram w=-2.
__constant__ int g1_tab[10][4] = {      // c=128 -> 2x2 grid of 64-tiles
    {0,0,0,1},{0,0,1,2},{0,1,1,1},
    {1,0,0,1},{1,0,1,2},{1,1,1,1},
    {2,0,0,-2},{2,0,1,-2},{2,1,0,-2},{2,1,1,-2},
};
__constant__ int g2_tab[36][4] = {      // c=256 -> 4x4 grid of 64-tiles
    {0,0,0,1},{0,0,1,2},{0,0,2,2},{0,0,3,2},{0,1,1,1},{0,1,2,2},{0,1,3,2},{0,2,2,1},{0,2,3,2},{0,3,3,1},
    {1,0,0,1},{1,0,1,2},{1,0,2,2},{1,0,3,2},{1,1,1,1},{1,1,2,2},{1,1,3,2},{1,2,2,1},{1,2,3,2},{1,3,3,1},
    {2,0,0,-2},{2,0,1,-2},{2,0,2,-2},{2,0,3,-2},
    {2,1,0,-2},{2,1,1,-2},{2,1,2,-2},{2,1,3,-2},
    {2,2,0,-2},{2,2,1,-2},{2,2,2,-2},{2,2,3,-2},
    {2,3,0,-2},{2,3,1,-2},{2,3,2,-2},{2,3,3,-2},
};

// ------------- prep: per-pixel norm + normalize + bf16 convert -------------
__global__ __launch_bounds__(256) void prep_kernel(
    const float* __restrict__ x1t, const float* __restrict__ x1s,
    const float* __restrict__ x2t, const float* __restrict__ x2s,
    short* __restrict__ F)
{
    int gp = blockIdx.x * 128;
    const float* x; short* f; int c, hw, base;
    if (gp < 16384)      { x = x1t; f = F + F1T; c = 128; hw = 4096; base = 0; }
    else if (gp < 32768) { x = x1s; f = F + F1S; c = 128; hw = 4096; base = 16384; }
    else if (gp < 36864) { x = x2t; f = F + F2T; c = 256; hw = 1024; base = 32768; }
    else                 { x = x2s; f = F + F2S; c = 256; hw = 1024; base = 36864; }
    const int t = threadIdx.x, lanei = t & 31, slice = t >> 5;
    int lp = gp - base + lanei * 4;      // blocks never straddle b or tensor
    int b = lp / hw, m = lp - b * hw;
    const float* p = x + (size_t)b * c * hw + m;
    short*       q = f + (size_t)b * c * hw + m;
    const int cpr = c >> 3;
    float4 s = {0.f, 0.f, 0.f, 0.f};
    for (int r = slice * cpr; r < (slice + 1) * cpr; ++r) {
        float4 v = *(const float4*)(p + (size_t)r * hw);
        s.x += v.x * v.x; s.y += v.y * v.y; s.z += v.z * v.z; s.w += v.w * v.w;
    }
    __shared__ float4 red[8][32];
    __shared__ float4 invl[32];
    red[slice][lanei] = s;
    __syncthreads();
    if (t < 32) {
        float4 tot = {0.f, 0.f, 0.f, 0.f};
#pragma unroll
        for (int sl = 0; sl < 8; ++sl) {
            float4 v = red[sl][t];
            tot.x += v.x; tot.y += v.y; tot.z += v.z; tot.w += v.w;
        }
        invl[t] = (float4){ 1.f / (sqrtf(tot.x) + EPSF), 1.f / (sqrtf(tot.y) + EPSF),
                            1.f / (sqrtf(tot.z) + EPSF), 1.f / (sqrtf(tot.w) + EPSF) };
    }
    __syncthreads();
    const float4 iv = invl[lanei];
    for (int r = slice * cpr; r < (slice + 1) * cpr; ++r) {
        float4 v = *(const float4*)(p + (size_t)r * hw);
        short4v o = { f2bf(v.x * iv.x), f2bf(v.y * iv.y),
                      f2bf(v.z * iv.z), f2bf(v.w * iv.w) };
        *(short4v*)(q + (size_t)r * hw) = o;
    }
}

// ------------- gram tile body: global-load -> MFMA, 4 iters of k=32 --------
template<int HW, bool SHARE>
__device__ inline void gram_body(const short* __restrict__ Fa,
                                 const short* __restrict__ Fb,
                                 int k0, int lane, float4v (&acc)[4][4])
{
    const int r16 = lane & 15, quad = lane >> 4;
    const int kb = k0 + quad * 8;
#pragma unroll 2
    for (int it = 0; it < 4; ++it) {
        short8v af[4], bfr[4];
#pragma unroll
        for (int rt = 0; rt < 4; ++rt)
            af[rt] = *(const short8v*)(Fa + (size_t)(rt * 16 + r16) * HW + kb + it * 32);
        if (SHARE) {
#pragma unroll
            for (int ct = 0; ct < 4; ++ct) bfr[ct] = af[ct];
        } else {
#pragma unroll
            for (int ct = 0; ct < 4; ++ct)
                bfr[ct] = *(const short8v*)(Fb + (size_t)(ct * 16 + r16) * HW + kb + it * 32);
        }
#pragma unroll
        for (int rt = 0; rt < 4; ++rt)
#pragma unroll
            for (int ct = 0; ct < 4; ++ct)
                acc[rt][ct] = __builtin_amdgcn_mfma_f32_16x16x32_bf16(
                    af[rt], bfr[ct], acc[rt][ct], 0, 0, 0);
    }
}

// ------------- stage A: 608 uniform blocks x 256 thr -----------------------
// Block = 64x64 tile x 512-px k-chunk (4 waves x 128 px). Combines its 4 wave
// partials in LDS and writes a LINEAR fp32 k-partial tile to ws. Squaring is
// deferred to stage B (sum over k-chunks must precede the square!).
// g1: 10 combos x 4 b x 8 ks = 320 blocks -> partial slot id
// g2: 36 combos x 4 b x 2 ks = 288 blocks -> slot 320 + id2
__global__ __launch_bounds__(256, 3) void gramA_kernel(
    const short* __restrict__ F, float* __restrict__ partials)
{
    __shared__ float buf[2][64 * 68];    // stride-68: 2-way bank alias (free)

    const int id = blockIdx.x;
    const int t = threadIdx.x, w = t >> 6, lane = t & 63;
    const int r16 = lane & 15, quad = lane >> 4;

    float4v acc[4][4];
#pragma unroll
    for (int i = 0; i < 4; ++i)
#pragma unroll
        for (int j = 0; j < 4; ++j) acc[i][j] = (float4v){0.f, 0.f, 0.f, 0.f};

    if (id < 320) {                      // group 1: c=128, hw=4096
        const int comb = id >> 5, sub = id & 31;
        const int b = sub >> 3, ks = sub & 7;
        const int g = g1_tab[comb][0];
        const int ra = g1_tab[comb][1] << 6, rb = g1_tab[comb][2] << 6;
        const short* Fa = (g == 1 ? F + F1S : F + F1T) + (size_t)(b * 128 + ra) * 4096;
        const short* Fb = (g == 0 ? F + F1T : F + F1S) + (size_t)(b * 128 + rb) * 4096;
        const int k0 = ks * 512 + w * 128;
        if (g < 2 && ra == rb) gram_body<4096, true >(Fa, Fa, k0, lane, acc);
        else                   gram_body<4096, false>(Fa, Fb, k0, lane, acc);
    } else {                             // group 2: c=256, hw=1024
        const int id2 = id - 320;
        const int comb = id2 >> 3, sub = id2 & 7;
        const int b = sub >> 1, ks = sub & 1;
        const int g = g2_tab[comb][0];
        const int ra = g2_tab[comb][1] << 6, rb = g2_tab[comb][2] << 6;
        const short* Fa = (g == 1 ? F + F2S : F + F2T) + (size_t)(b * 256 + ra) * 1024;
        const short* Fb = (g == 0 ? F + F2T : F + F2S) + (size_t)(b * 256 + rb) * 1024;
        const int k0 = ks * 512 + w * 128;
        if (g < 2 && ra == rb) gram_body<1024, true >(Fa, Fa, k0, lane, acc);
        else                   gram_body<1024, false>(Fa, Fb, k0, lane, acc);
    }

    // ---- combine 4 wave partials (2 rounds, 2 buffers) --------------------
    // C/D layout: col = lane&15, row = quad*4 + reg.
#pragma unroll 1
    for (int rr = 0; rr < 2; ++rr) {
        if ((w >> 1) == rr) {
            float* dst = buf[w & 1];
#pragma unroll
            for (int rt = 0; rt < 4; ++rt)
#pragma unroll
                for (int ct = 0; ct < 4; ++ct)
#pragma unroll
                    for (int r = 0; r < 4; ++r) {
                        int off = (rt * 16 + quad * 4 + r) * 68 + ct * 16 + r16;
                        if (rr == 0) dst[off] = acc[rt][ct][r];
                        else         dst[off] += acc[rt][ct][r];
                    }
        }
        __syncthreads();
    }
    // ---- write linear 64x64 fp32 k-partial (coalesced dwords) -------------
    float* dst = partials + (size_t)id * 4096;
#pragma unroll
    for (int i = 0; i < 16; ++i) {
        int cell = (i << 8) + t;         // lane-consecutive: coalesced store
        int off = (cell >> 6) * 68 + (cell & 63);   // conflict-free LDS read
        dst[cell] = buf[0][off] + buf[1][off];
    }
}

// ------------- stage B: 184 blocks; sum k-partials, square, weight ---------
// g1 tile T=comb*4+b (0..39): partial slots comb*32+b*8+ks, ks=0..7
// g2 tile 40+comb*4+b: slots 320+comb*8+b*2+ks, ks=0..1
// Atomic-adds the weighted Frobenius contribution directly into d_out.
__global__ __launch_bounds__(256) void gramB_kernel(
    const float* __restrict__ partials, float* __restrict__ out)
{
    __shared__ float scratch[256];
    const int tile = blockIdx.x, t = threadIdx.x;
    const float* base; int P, stride; float wt; int which;
    if (tile < 40) {
        const int comb = tile >> 2, b = tile & 3;
        base = partials + (size_t)(comb * 32 + b * 8) * 4096;
        P = 8; stride = 4096;
        wt = (float)g1_tab[comb][3] * (1.0f / (4096.f * 4096.f * 4.f));
        which = 2;
    } else {
        const int t2 = tile - 40;
        const int comb = t2 >> 2, b = t2 & 3;
        base = partials + (size_t)(320 + comb * 8 + b * 2) * 4096;
        P = 2; stride = 4096;
        wt = (float)g2_tab[comb][3] * (1.0f / (1024.f * 1024.f * 4.f));
        which = 3;
    }
    float s = 0.f;
#pragma unroll
    for (int i = 0; i < 4; ++i) {
        int c4 = i * 1024 + t * 4;       // float4 lane-consecutive: coalesced
        float4 v = {0.f, 0.f, 0.f, 0.f};
        for (int p = 0; p < P; ++p) {
            float4 u = *(const float4*)(base + (size_t)p * stride + c4);
            v.x += u.x; v.y += u.y; v.z += u.z; v.w += u.w;
        }
        s += v.x * v.x + v.y * v.y + v.z * v.z + v.w * v.w;
    }
    s *= wt;
    scratch[t] = s;
    __syncthreads();
    for (int off = 128; off > 0; off >>= 1) {
        if (t < off) scratch[t] += scratch[t + off];
        __syncthreads();
    }
    if (t == 0) {
        float v = scratch[0];
        atomicAdd(&out[0], v);           // loss
        atomicAdd(&out[1], v);           // stack[0] = loss
        atomicAdd(&out[which], v);       // stack[1]=pwl_g1 / stack[2]=pwl_g2
    }
}

extern "C" void kernel_launch(void* const* d_in, const int* in_sizes, int n_in,
                              void* d_out, int out_size, void* d_ws, size_t ws_size,
                              hipStream_t stream)
{
    const float* x1t = (const float*)d_in[0];   // [4,128,64,64]
    const float* x1s = (const float*)d_in[1];
    const float* x2t = (const float*)d_in[2];   // [4,256,32,32]
    const float* x2s = (const float*)d_in[3];

    short* F        = (short*)d_ws;              // 6291456 shorts (12.6 MB)
    float* partials = (float*)d_ws + 3200000;    // 608 x 4096 floats (10 MB)

    hipMemsetAsync(d_out, 0, 4 * sizeof(float), stream);
    prep_kernel<<<320, 256, 0, stream>>>(x1t, x1s, x2t, x2s, F);
    gramA_kernel<<<608, 256, 0, stream>>>(F, partials);
    gramB_kernel<<<184, 256, 0, stream>>>(partials, (float*)d_out);
}

// Round 8
// 109.386 us; speedup vs baseline: 1.0957x; 1.0957x over previous
//
#include <hip/hip_runtime.h>
#include <math.h>

#define EPSF 1e-8f

typedef __attribute__((ext_vector_type(4))) short short4v;
typedef __attribute__((ext_vector_type(8))) short short8v;
typedef __attribute__((ext_vector_type(4))) float float4v;

__device__ inline short f2bf(float f) {
    unsigned u = __builtin_bit_cast(unsigned, f);
    unsigned r = (u + 0x7FFFu + ((u >> 16) & 1u)) >> 16;
    return (short)r;
}

// F layout (bf16 shorts): f1t @0 (4*128*4096), f1s @2097152, f2t @4194304
// (4*256*1024), f2s @5242880; total 6291456 shorts = 12.6 MB.
#define F1T 0
#define F1S 2097152
#define F2T 4194304
#define F2S 5242880

// Sub-tile combos {g, ri, rj, w}; tile unit = 64 rows. g: 0=t*t 1=s*s 2=t*s.
// Diagonal grams symmetric: upper triangle; diag tile w=1, off-diag w=2;
// cross gram w=-2.
__constant__ int g1_tab[10][4] = {      // c=128 -> 2x2 grid of 64-tiles
    {0,0,0,1},{0,0,1,2},{0,1,1,1},
    {1,0,0,1},{1,0,1,2},{1,1,1,1},
    {2,0,0,-2},{2,0,1,-2},{2,1,0,-2},{2,1,1,-2},
};
__constant__ int g2_tab[36][4] = {      // c=256 -> 4x4 grid of 64-tiles
    {0,0,0,1},{0,0,1,2},{0,0,2,2},{0,0,3,2},{0,1,1,1},{0,1,2,2},{0,1,3,2},{0,2,2,1},{0,2,3,2},{0,3,3,1},
    {1,0,0,1},{1,0,1,2},{1,0,2,2},{1,0,3,2},{1,1,1,1},{1,1,2,2},{1,1,3,2},{1,2,2,1},{1,2,3,2},{1,3,3,1},
    {2,0,0,-2},{2,0,1,-2},{2,0,2,-2},{2,0,3,-2},
    {2,1,0,-2},{2,1,1,-2},{2,1,2,-2},{2,1,3,-2},
    {2,2,0,-2},{2,2,1,-2},{2,2,2,-2},{2,2,3,-2},
    {2,3,0,-2},{2,3,1,-2},{2,3,2,-2},{2,3,3,-2},
};

// ------------- prep: per-pixel norm + normalize + bf16 convert -------------
// Templated: constexpr trip counts -> full unroll, many loads in flight.
template<int C, int HW>
__device__ inline void prep_body(const float* __restrict__ x,
                                 short* __restrict__ f, int lp, int t)
{
    const int lanei = t & 31, slice = t >> 5;
    const int b = lp / HW, m = lp - b * HW;
    const float* p = x + (size_t)b * C * HW + m;
    short*       q = f + (size_t)b * C * HW + m;
    constexpr int CPR = C >> 3;          // rows per slice (16 or 32)
    float4 s0 = {0.f,0.f,0.f,0.f}, s1 = {0.f,0.f,0.f,0.f};
#pragma unroll
    for (int i = 0; i < CPR; i += 2) {
        float4 v0 = *(const float4*)(p + (size_t)(slice * CPR + i)     * HW);
        float4 v1 = *(const float4*)(p + (size_t)(slice * CPR + i + 1) * HW);
        s0.x += v0.x * v0.x; s0.y += v0.y * v0.y;
        s0.z += v0.z * v0.z; s0.w += v0.w * v0.w;
        s1.x += v1.x * v1.x; s1.y += v1.y * v1.y;
        s1.z += v1.z * v1.z; s1.w += v1.w * v1.w;
    }
    float4 s = { s0.x + s1.x, s0.y + s1.y, s0.z + s1.z, s0.w + s1.w };
    __shared__ float4 red[8][32];
    __shared__ float4 invl[32];
    red[slice][lanei] = s;
    __syncthreads();
    if (t < 32) {
        float4 tot = {0.f,0.f,0.f,0.f};
#pragma unroll
        for (int sl = 0; sl < 8; ++sl) {
            float4 v = red[sl][t];
            tot.x += v.x; tot.y += v.y; tot.z += v.z; tot.w += v.w;
        }
        invl[t] = (float4){ 1.f / (sqrtf(tot.x) + EPSF), 1.f / (sqrtf(tot.y) + EPSF),
                            1.f / (sqrtf(tot.z) + EPSF), 1.f / (sqrtf(tot.w) + EPSF) };
    }
    __syncthreads();
    const float4 iv = invl[lanei];
#pragma unroll
    for (int i = 0; i < CPR; ++i) {
        const int r = slice * CPR + i;
        float4 v = *(const float4*)(p + (size_t)r * HW);
        short4v o = { f2bf(v.x * iv.x), f2bf(v.y * iv.y),
                      f2bf(v.z * iv.z), f2bf(v.w * iv.w) };
        *(short4v*)(q + (size_t)r * HW) = o;
    }
}

__global__ __launch_bounds__(256) void prep_kernel(
    const float* __restrict__ x1t, const float* __restrict__ x1s,
    const float* __restrict__ x2t, const float* __restrict__ x2s,
    short* __restrict__ F)
{
    const int gp = blockIdx.x * 128;
    const int t = threadIdx.x;
    const int lanei = t & 31;
    if (gp < 16384)
        prep_body<128, 4096>(x1t, F + F1T, gp + lanei * 4, t);
    else if (gp < 32768)
        prep_body<128, 4096>(x1s, F + F1S, gp - 16384 + lanei * 4, t);
    else if (gp < 36864)
        prep_body<256, 1024>(x2t, F + F2T, gp - 32768 + lanei * 4, t);
    else
        prep_body<256, 1024>(x2s, F + F2S, gp - 36864 + lanei * 4, t);
}

// ------------- gram tile body: straight-line, all loads up front -----------
// 4 k-steps of 32 px fully unrolled: up to 32 independent 16B loads issue
// before the first MFMA; single latency exposure per wave.
template<int HW, bool SHARE>
__device__ inline void gram_body(const short* __restrict__ Fa,
                                 const short* __restrict__ Fb,
                                 int k0, int lane, float4v (&acc)[4][4])
{
    const int r16 = lane & 15, quad = lane >> 4;
    const int kb = k0 + quad * 8;
    short8v af[4][4], bfr[4][4];
#pragma unroll
    for (int it = 0; it < 4; ++it)
#pragma unroll
        for (int rt = 0; rt < 4; ++rt)
            af[it][rt] = *(const short8v*)(Fa + (size_t)(rt * 16 + r16) * HW + kb + it * 32);
    if (!SHARE) {
#pragma unroll
        for (int it = 0; it < 4; ++it)
#pragma unroll
            for (int ct = 0; ct < 4; ++ct)
                bfr[it][ct] = *(const short8v*)(Fb + (size_t)(ct * 16 + r16) * HW + kb + it * 32);
    }
#pragma unroll
    for (int it = 0; it < 4; ++it)
#pragma unroll
        for (int rt = 0; rt < 4; ++rt)
#pragma unroll
            for (int ct = 0; ct < 4; ++ct)
                acc[rt][ct] = __builtin_amdgcn_mfma_f32_16x16x32_bf16(
                    af[it][rt], SHARE ? af[it][ct] : bfr[it][ct],
                    acc[rt][ct], 0, 0, 0);
}

// ------------- stage A: 608 uniform blocks x 256 thr -----------------------
// Block = 64x64 tile x 512-px k-chunk (4 waves x 128 px). Combines its 4 wave
// partials in LDS, writes a LINEAR fp32 k-partial tile to ws (square deferred
// to stage B: sum over k must precede the square).
__global__ __launch_bounds__(256, 2) void gramA_kernel(
    const short* __restrict__ F, float* __restrict__ partials)
{
    __shared__ float buf[2][64 * 68];    // stride-68: 2-way bank alias (free)

    const int id = blockIdx.x;
    const int t = threadIdx.x, w = t >> 6, lane = t & 63;
    const int r16 = lane & 15, quad = lane >> 4;

    float4v acc[4][4];
#pragma unroll
    for (int i = 0; i < 4; ++i)
#pragma unroll
        for (int j = 0; j < 4; ++j) acc[i][j] = (float4v){0.f, 0.f, 0.f, 0.f};

    if (id < 320) {                      // group 1: c=128, hw=4096
        const int comb = id >> 5, sub = id & 31;
        const int b = sub >> 3, ks = sub & 7;
        const int g = g1_tab[comb][0];
        const int ra = g1_tab[comb][1] << 6, rb = g1_tab[comb][2] << 6;
        const short* Fa = (g == 1 ? F + F1S : F + F1T) + (size_t)(b * 128 + ra) * 4096;
        const short* Fb = (g == 0 ? F + F1T : F + F1S) + (size_t)(b * 128 + rb) * 4096;
        const int k0 = ks * 512 + w * 128;
        if (g < 2 && ra == rb) gram_body<4096, true >(Fa, Fa, k0, lane, acc);
        else                   gram_body<4096, false>(Fa, Fb, k0, lane, acc);
    } else {                             // group 2: c=256, hw=1024
        const int id2 = id - 320;
        const int comb = id2 >> 3, sub = id2 & 7;
        const int b = sub >> 1, ks = sub & 1;
        const int g = g2_tab[comb][0];
        const int ra = g2_tab[comb][1] << 6, rb = g2_tab[comb][2] << 6;
        const short* Fa = (g == 1 ? F + F2S : F + F2T) + (size_t)(b * 256 + ra) * 1024;
        const short* Fb = (g == 0 ? F + F2T : F + F2S) + (size_t)(b * 256 + rb) * 1024;
        const int k0 = ks * 512 + w * 128;
        if (g < 2 && ra == rb) gram_body<1024, true >(Fa, Fa, k0, lane, acc);
        else                   gram_body<1024, false>(Fa, Fb, k0, lane, acc);
    }

    // ---- combine 4 wave partials (2 rounds, 2 buffers) --------------------
    // C/D layout: col = lane&15, row = quad*4 + reg.
#pragma unroll 1
    for (int rr = 0; rr < 2; ++rr) {
        if ((w >> 1) == rr) {
            float* dst = buf[w & 1];
#pragma unroll
            for (int rt = 0; rt < 4; ++rt)
#pragma unroll
                for (int ct = 0; ct < 4; ++ct)
#pragma unroll
                    for (int r = 0; r < 4; ++r) {
                        int off = (rt * 16 + quad * 4 + r) * 68 + ct * 16 + r16;
                        if (rr == 0) dst[off] = acc[rt][ct][r];
                        else         dst[off] += acc[rt][ct][r];
                    }
        }
        __syncthreads();
    }
    // ---- write linear 64x64 fp32 k-partial (coalesced dwords) -------------
    float* dst = partials + (size_t)id * 4096;
#pragma unroll
    for (int i = 0; i < 16; ++i) {
        int cell = (i << 8) + t;         // lane-consecutive: coalesced store
        int off = (cell >> 6) * 68 + (cell & 63);   // conflict-free LDS read
        dst[cell] = buf[0][off] + buf[1][off];
    }
}

// ------------- stage B: 184 blocks; sum k-partials, square, weight ---------
template<int P>
__device__ inline float gramB_sum(const float* __restrict__ base, int t)
{
    float s = 0.f;
#pragma unroll
    for (int i = 0; i < 4; ++i) {
        const int c4 = i * 1024 + t * 4; // float4 lane-consecutive: coalesced
        float4 v = {0.f, 0.f, 0.f, 0.f};
#pragma unroll
        for (int p = 0; p < P; ++p) {
            float4 u = *(const float4*)(base + (size_t)p * 4096 + c4);
            v.x += u.x; v.y += u.y; v.z += u.z; v.w += u.w;
        }
        s += v.x * v.x + v.y * v.y + v.z * v.z + v.w * v.w;
    }
    return s;
}

__global__ __launch_bounds__(256) void gramB_kernel(
    const float* __restrict__ partials, float* __restrict__ out)
{
    __shared__ float scratch[256];
    const int tile = blockIdx.x, t = threadIdx.x;
    float s, wt; int which;
    if (tile < 40) {
        const int comb = tile >> 2, b = tile & 3;
        s = gramB_sum<8>(partials + (size_t)(comb * 32 + b * 8) * 4096, t);
        wt = (float)g1_tab[comb][3] * (1.0f / (4096.f * 4096.f * 4.f));
        which = 2;
    } else {
        const int t2 = tile - 40;
        const int comb = t2 >> 2, b = t2 & 3;
        s = gramB_sum<2>(partials + (size_t)(320 + comb * 8 + b * 2) * 4096, t);
        wt = (float)g2_tab[comb][3] * (1.0f / (1024.f * 1024.f * 4.f));
        which = 3;
    }
    s *= wt;
    scratch[t] = s;
    __syncthreads();
    for (int off = 128; off > 0; off >>= 1) {
        if (t < off) scratch[t] += scratch[t + off];
        __syncthreads();
    }
    if (t == 0) {
        float v = scratch[0];
        atomicAdd(&out[0], v);           // loss
        atomicAdd(&out[1], v);           // stack[0] = loss
        atomicAdd(&out[which], v);       // stack[1]=pwl_g1 / stack[2]=pwl_g2
    }
}

extern "C" void kernel_launch(void* const* d_in, const int* in_sizes, int n_in,
                              void* d_out, int out_size, void* d_ws, size_t ws_size,
                              hipStream_t stream)
{
    const float* x1t = (const float*)d_in[0];   // [4,128,64,64]
    const float* x1s = (const float*)d_in[1];
    const float* x2t = (const float*)d_in[2];   // [4,256,32,32]
    const float* x2s = (const float*)d_in[3];

    short* F        = (short*)d_ws;              // 6291456 shorts (12.6 MB)
    float* partials = (float*)d_ws + 3200000;    // 608 x 4096 floats (10 MB)

    hipMemsetAsync(d_out, 0, 4 * sizeof(float), stream);
    prep_kernel<<<320, 256, 0, stream>>>(x1t, x1s, x2t, x2s, F);
    gramA_kernel<<<608, 256, 0, stream>>>(F, partials);
    gramB_kernel<<<184, 256, 0, stream>>>(partials, (float*)d_out);
}

// Round 9
// 107.024 us; speedup vs baseline: 1.1199x; 1.0221x over previous
//
#include <hip/hip_runtime.h>
#include <math.h>

#define EPSF 1e-8f

typedef __attribute__((ext_vector_type(4))) short short4v;
typedef __attribute__((ext_vector_type(8))) short short8v;
typedef __attribute__((ext_vector_type(4))) float float4v;

__device__ inline short f2bf(float f) {
    unsigned u = __builtin_bit_cast(unsigned, f);
    unsigned r = (u + 0x7FFFu + ((u >> 16) & 1u)) >> 16;
    return (short)r;
}
__device__ inline float bf2f(short s) {
    unsigned u = ((unsigned)(unsigned short)s) << 16;
    return __builtin_bit_cast(float, u);
}

// F layout (bf16 shorts): f1t @0 (4*128*4096), f1s @2097152, f2t @4194304
// (4*256*1024), f2s @5242880; total 6291456 shorts = 12.6 MB.
#define F1T 0
#define F1S 2097152
#define F2T 4194304
#define F2S 5242880

// Sub-tile combos {g, ri, rj, w}; tile unit = 64 rows. g: 0=t*t 1=s*s 2=t*s.
// Diagonal grams symmetric: upper triangle; diag tile w=1, off-diag w=2;
// cross gram w=-2.
__constant__ int g1_tab[10][4] = {      // c=128 -> 2x2 grid of 64-tiles
    {0,0,0,1},{0,0,1,2},{0,1,1,1},
    {1,0,0,1},{1,0,1,2},{1,1,1,1},
    {2,0,0,-2},{2,0,1,-2},{2,1,0,-2},{2,1,1,-2},
};
__constant__ int g2_tab[36][4] = {      // c=256 -> 4x4 grid of 64-tiles
    {0,0,0,1},{0,0,1,2},{0,0,2,2},{0,0,3,2},{0,1,1,1},{0,1,2,2},{0,1,3,2},{0,2,2,1},{0,2,3,2},{0,3,3,1},
    {1,0,0,1},{1,0,1,2},{1,0,2,2},{1,0,3,2},{1,1,1,1},{1,1,2,2},{1,1,3,2},{1,2,2,1},{1,2,3,2},{1,3,3,1},
    {2,0,0,-2},{2,0,1,-2},{2,0,2,-2},{2,0,3,-2},
    {2,1,0,-2},{2,1,1,-2},{2,1,2,-2},{2,1,3,-2},
    {2,2,0,-2},{2,2,1,-2},{2,2,2,-2},{2,2,3,-2},
    {2,3,0,-2},{2,3,1,-2},{2,3,2,-2},{2,3,3,-2},
};

// ------------- prep: single-pass norm + normalize + bf16 convert -----------
// Raw values stashed in REGISTERS as packed bf16 during the squares pass;
// phase 2 unpacks, scales by invn, re-rounds, stores. Inputs read ONCE.
template<int C, int HW>
__device__ inline void prep_body(const float* __restrict__ x,
                                 short* __restrict__ f, int lp, int t)
{
    const int lanei = t & 31, slice = t >> 5;
    const int b = lp / HW, m = lp - b * HW;
    const float* p = x + (size_t)b * C * HW + m;
    short*       q = f + (size_t)b * C * HW + m;
    constexpr int CPR = C >> 3;          // rows per slice (16 or 32)
    short4v vals[CPR];
    float4 s0 = {0.f,0.f,0.f,0.f}, s1 = {0.f,0.f,0.f,0.f};
#pragma unroll
    for (int i = 0; i < CPR; i += 2) {
        float4 v0 = *(const float4*)(p + (size_t)(slice * CPR + i)     * HW);
        float4 v1 = *(const float4*)(p + (size_t)(slice * CPR + i + 1) * HW);
        s0.x += v0.x * v0.x; s0.y += v0.y * v0.y;
        s0.z += v0.z * v0.z; s0.w += v0.w * v0.w;
        s1.x += v1.x * v1.x; s1.y += v1.y * v1.y;
        s1.z += v1.z * v1.z; s1.w += v1.w * v1.w;
        vals[i]     = (short4v){ f2bf(v0.x), f2bf(v0.y), f2bf(v0.z), f2bf(v0.w) };
        vals[i + 1] = (short4v){ f2bf(v1.x), f2bf(v1.y), f2bf(v1.z), f2bf(v1.w) };
    }
    float4 s = { s0.x + s1.x, s0.y + s1.y, s0.z + s1.z, s0.w + s1.w };
    __shared__ float4 red[8][32];
    __shared__ float4 invl[32];
    red[slice][lanei] = s;
    __syncthreads();
    if (t < 32) {
        float4 tot = {0.f,0.f,0.f,0.f};
#pragma unroll
        for (int sl = 0; sl < 8; ++sl) {
            float4 v = red[sl][t];
            tot.x += v.x; tot.y += v.y; tot.z += v.z; tot.w += v.w;
        }
        invl[t] = (float4){ 1.f / (sqrtf(tot.x) + EPSF), 1.f / (sqrtf(tot.y) + EPSF),
                            1.f / (sqrtf(tot.z) + EPSF), 1.f / (sqrtf(tot.w) + EPSF) };
    }
    __syncthreads();
    const float4 iv = invl[lanei];
#pragma unroll
    for (int i = 0; i < CPR; ++i) {
        const int r = slice * CPR + i;
        short4v rv = vals[i];
        short4v o = { f2bf(bf2f(rv[0]) * iv.x), f2bf(bf2f(rv[1]) * iv.y),
                      f2bf(bf2f(rv[2]) * iv.z), f2bf(bf2f(rv[3]) * iv.w) };
        *(short4v*)(q + (size_t)r * HW) = o;
    }
}

__global__ __launch_bounds__(256) void prep_kernel(
    const float* __restrict__ x1t, const float* __restrict__ x1s,
    const float* __restrict__ x2t, const float* __restrict__ x2s,
    short* __restrict__ F, float* __restrict__ out)
{
    const int gp = blockIdx.x * 128;
    const int t = threadIdx.x;
    const int lanei = t & 31;
    if (blockIdx.x == 0 && t < 4) out[t] = 0.f;   // replaces memset dispatch
    if (gp < 16384)
        prep_body<128, 4096>(x1t, F + F1T, gp + lanei * 4, t);
    else if (gp < 32768)
        prep_body<128, 4096>(x1s, F + F1S, gp - 16384 + lanei * 4, t);
    else if (gp < 36864)
        prep_body<256, 1024>(x2t, F + F2T, gp - 32768 + lanei * 4, t);
    else
        prep_body<256, 1024>(x2s, F + F2S, gp - 36864 + lanei * 4, t);
}

// ------------- gram tile body: two half-bodies of 2 k-steps ----------------
// 16 loads in flight per half (~160 VGPR total) -> 3 blocks/CU resident,
// trading one extra (L2-warm) latency exposure for 1.5x more TLP.
template<int HW, bool SHARE>
__device__ inline void gram_body(const short* __restrict__ Fa,
                                 const short* __restrict__ Fb,
                                 int k0, int lane, float4v (&acc)[4][4])
{
    const int r16 = lane & 15, quad = lane >> 4;
    const int kb = k0 + quad * 8;
#pragma unroll
    for (int half = 0; half < 2; ++half) {
        short8v af[2][4], bfr[2][4];
#pragma unroll
        for (int it = 0; it < 2; ++it)
#pragma unroll
            for (int rt = 0; rt < 4; ++rt)
                af[it][rt] = *(const short8v*)(
                    Fa + (size_t)(rt * 16 + r16) * HW + kb + (half * 2 + it) * 32);
        if (!SHARE) {
#pragma unroll
            for (int it = 0; it < 2; ++it)
#pragma unroll
                for (int ct = 0; ct < 4; ++ct)
                    bfr[it][ct] = *(const short8v*)(
                        Fb + (size_t)(ct * 16 + r16) * HW + kb + (half * 2 + it) * 32);
        }
#pragma unroll
        for (int it = 0; it < 2; ++it)
#pragma unroll
            for (int rt = 0; rt < 4; ++rt)
#pragma unroll
                for (int ct = 0; ct < 4; ++ct)
                    acc[rt][ct] = __builtin_amdgcn_mfma_f32_16x16x32_bf16(
                        af[it][rt], SHARE ? af[it][ct] : bfr[it][ct],
                        acc[rt][ct], 0, 0, 0);
    }
}

// ------------- stage A: 608 uniform blocks x 256 thr -----------------------
// Block = 64x64 tile x 512-px k-chunk (4 waves x 128 px). Combines its 4 wave
// partials in LDS, writes a LINEAR fp32 k-partial tile to ws (square deferred
// to stage B: sum over k must precede the square).
__global__ __launch_bounds__(256, 3) void gramA_kernel(
    const short* __restrict__ F, float* __restrict__ partials)
{
    __shared__ float buf[2][64 * 68];    // stride-68: 2-way bank alias (free)

    const int id = blockIdx.x;
    const int t = threadIdx.x, w = t >> 6, lane = t & 63;
    const int r16 = lane & 15, quad = lane >> 4;

    float4v acc[4][4];
#pragma unroll
    for (int i = 0; i < 4; ++i)
#pragma unroll
        for (int j = 0; j < 4; ++j) acc[i][j] = (float4v){0.f, 0.f, 0.f, 0.f};

    if (id < 320) {                      // group 1: c=128, hw=4096
        const int comb = id >> 5, sub = id & 31;
        const int b = sub >> 3, ks = sub & 7;
        const int g = g1_tab[comb][0];
        const int ra = g1_tab[comb][1] << 6, rb = g1_tab[comb][2] << 6;
        const short* Fa = (g == 1 ? F + F1S : F + F1T) + (size_t)(b * 128 + ra) * 4096;
        const short* Fb = (g == 0 ? F + F1T : F + F1S) + (size_t)(b * 128 + rb) * 4096;
        const int k0 = ks * 512 + w * 128;
        if (g < 2 && ra == rb) gram_body<4096, true >(Fa, Fa, k0, lane, acc);
        else                   gram_body<4096, false>(Fa, Fb, k0, lane, acc);
    } else {                             // group 2: c=256, hw=1024
        const int id2 = id - 320;
        const int comb = id2 >> 3, sub = id2 & 7;
        const int b = sub >> 1, ks = sub & 1;
        const int g = g2_tab[comb][0];
        const int ra = g2_tab[comb][1] << 6, rb = g2_tab[comb][2] << 6;
        const short* Fa = (g == 1 ? F + F2S : F + F2T) + (size_t)(b * 256 + ra) * 1024;
        const short* Fb = (g == 0 ? F + F2T : F + F2S) + (size_t)(b * 256 + rb) * 1024;
        const int k0 = ks * 512 + w * 128;
        if (g < 2 && ra == rb) gram_body<1024, true >(Fa, Fa, k0, lane, acc);
        else                   gram_body<1024, false>(Fa, Fb, k0, lane, acc);
    }

    // ---- combine 4 wave partials (2 rounds, 2 buffers) --------------------
    // C/D layout: col = lane&15, row = quad*4 + reg.
#pragma unroll 1
    for (int rr = 0; rr < 2; ++rr) {
        if ((w >> 1) == rr) {
            float* dst = buf[w & 1];
#pragma unroll
            for (int rt = 0; rt < 4; ++rt)
#pragma unroll
                for (int ct = 0; ct < 4; ++ct)
#pragma unroll
                    for (int r = 0; r < 4; ++r) {
                        int off = (rt * 16 + quad * 4 + r) * 68 + ct * 16 + r16;
                        if (rr == 0) dst[off] = acc[rt][ct][r];
                        else         dst[off] += acc[rt][ct][r];
                    }
        }
        __syncthreads();
    }
    // ---- write linear 64x64 fp32 k-partial (coalesced dwords) -------------
    float* dst = partials + (size_t)id * 4096;
#pragma unroll
    for (int i = 0; i < 16; ++i) {
        int cell = (i << 8) + t;         // lane-consecutive: coalesced store
        int off = (cell >> 6) * 68 + (cell & 63);   // conflict-free LDS read
        dst[cell] = buf[0][off] + buf[1][off];
    }
}

// ------------- stage B: 184 blocks; sum k-partials, square, weight ---------
template<int P>
__device__ inline float gramB_sum(const float* __restrict__ base, int t)
{
    float s = 0.f;
#pragma unroll
    for (int i = 0; i < 4; ++i) {
        const int c4 = i * 1024 + t * 4; // float4 lane-consecutive: coalesced
        float4 v = {0.f, 0.f, 0.f, 0.f};
#pragma unroll
        for (int p = 0; p < P; ++p) {
            float4 u = *(const float4*)(base + (size_t)p * 4096 + c4);
            v.x += u.x; v.y += u.y; v.z += u.z; v.w += u.w;
        }
        s += v.x * v.x + v.y * v.y + v.z * v.z + v.w * v.w;
    }
    return s;
}

__global__ __launch_bounds__(256) void gramB_kernel(
    const float* __restrict__ partials, float* __restrict__ out)
{
    __shared__ float scratch[256];
    const int tile = blockIdx.x, t = threadIdx.x;
    float s, wt; int which;
    if (tile < 40) {
        const int comb = tile >> 2, b = tile & 3;
        s = gramB_sum<8>(partials + (size_t)(comb * 32 + b * 8) * 4096, t);
        wt = (float)g1_tab[comb][3] * (1.0f / (4096.f * 4096.f * 4.f));
        which = 2;
    } else {
        const int t2 = tile - 40;
        const int comb = t2 >> 2, b = t2 & 3;
        s = gramB_sum<2>(partials + (size_t)(320 + comb * 8 + b * 2) * 4096, t);
        wt = (float)g2_tab[comb][3] * (1.0f / (1024.f * 1024.f * 4.f));
        which = 3;
    }
    s *= wt;
    scratch[t] = s;
    __syncthreads();
    for (int off = 128; off > 0; off >>= 1) {
        if (t < off) scratch[t] += scratch[t + off];
        __syncthreads();
    }
    if (t == 0) {
        float v = scratch[0];
        atomicAdd(&out[0], v);           // loss
        atomicAdd(&out[1], v);           // stack[0] = loss
        atomicAdd(&out[which], v);       // stack[1]=pwl_g1 / stack[2]=pwl_g2
    }
}

extern "C" void kernel_launch(void* const* d_in, const int* in_sizes, int n_in,
                              void* d_out, int out_size, void* d_ws, size_t ws_size,
                              hipStream_t stream)
{
    const float* x1t = (const float*)d_in[0];   // [4,128,64,64]
    const float* x1s = (const float*)d_in[1];
    const float* x2t = (const float*)d_in[2];   // [4,256,32,32]
    const float* x2s = (const float*)d_in[3];

    short* F        = (short*)d_ws;              // 6291456 shorts (12.6 MB)
    float* partials = (float*)d_ws + 3200000;    // 608 x 4096 floats (10 MB)

    prep_kernel<<<320, 256, 0, stream>>>(x1t, x1s, x2t, x2s, F, (float*)d_out);
    gramA_kernel<<<608, 256, 0, stream>>>(F, partials);
    gramB_kernel<<<184, 256, 0, stream>>>(partials, (float*)d_out);
}

// Round 10
// 104.440 us; speedup vs baseline: 1.1476x; 1.0247x over previous
//
#include <hip/hip_runtime.h>
#include <math.h>

#define EPSF 1e-8f

typedef __attribute__((ext_vector_type(4))) short short4v;
typedef __attribute__((ext_vector_type(8))) short short8v;
typedef __attribute__((ext_vector_type(4))) float float4v;

__device__ inline short f2bf(float f) {
    unsigned u = __builtin_bit_cast(unsigned, f);
    unsigned r = (u + 0x7FFFu + ((u >> 16) & 1u)) >> 16;
    return (short)r;
}
__device__ inline float bf2f(short s) {
    unsigned u = ((unsigned)(unsigned short)s) << 16;
    return __builtin_bit_cast(float, u);
}

// F layout (bf16 shorts): f1t @0 (4*128*4096), f1s @2097152, f2t @4194304
// (4*256*1024), f2s @5242880; total 6291456 shorts = 12.6 MB.
#define F1T 0
#define F1S 2097152
#define F2T 4194304
#define F2S 5242880

// Sub-tile combos {g, ri, rj, w}; tile unit = 64 rows. g: 0=t*t 1=s*s 2=t*s.
// Diagonal grams symmetric: upper triangle; diag tile w=1, off-diag w=2;
// cross gram w=-2.
__constant__ int g1_tab[10][4] = {      // c=128 -> 2x2 grid of 64-tiles
    {0,0,0,1},{0,0,1,2},{0,1,1,1},
    {1,0,0,1},{1,0,1,2},{1,1,1,1},
    {2,0,0,-2},{2,0,1,-2},{2,1,0,-2},{2,1,1,-2},
};
__constant__ int g2_tab[36][4] = {      // c=256 -> 4x4 grid of 64-tiles
    {0,0,0,1},{0,0,1,2},{0,0,2,2},{0,0,3,2},{0,1,1,1},{0,1,2,2},{0,1,3,2},{0,2,2,1},{0,2,3,2},{0,3,3,1},
    {1,0,0,1},{1,0,1,2},{1,0,2,2},{1,0,3,2},{1,1,1,1},{1,1,2,2},{1,1,3,2},{1,2,2,1},{1,2,3,2},{1,3,3,1},
    {2,0,0,-2},{2,0,1,-2},{2,0,2,-2},{2,0,3,-2},
    {2,1,0,-2},{2,1,1,-2},{2,1,2,-2},{2,1,3,-2},
    {2,2,0,-2},{2,2,1,-2},{2,2,2,-2},{2,2,3,-2},
    {2,3,0,-2},{2,3,1,-2},{2,3,2,-2},{2,3,3,-2},
};

// ------------- prep: single-pass norm + normalize + bf16 convert -----------
// 1280 blocks x 32 px (fine granularity: max 5 blocks/CU -> ~1.25x imbalance
// vs the old 320x128 layout's 2x). 8 px-groups x 32 channel-slices.
// Raw values stashed in registers as packed bf16; inputs read ONCE.
template<int C, int HW>
__device__ inline void prep_body(const float* __restrict__ x,
                                 short* __restrict__ f, int lp, int t)
{
    const int lanei = t & 7, slice = t >> 3;     // 8 groups x 32 slices
    const int b = lp / HW, m = lp - b * HW;
    const float* p = x + (size_t)b * C * HW + m;
    short*       q = f + (size_t)b * C * HW + m;
    constexpr int CPR = C >> 5;          // rows per slice (4 or 8)
    short4v vals[CPR];
    float4 s0 = {0.f,0.f,0.f,0.f}, s1 = {0.f,0.f,0.f,0.f};
#pragma unroll
    for (int i = 0; i < CPR; i += 2) {
        float4 v0 = *(const float4*)(p + (size_t)(slice * CPR + i)     * HW);
        float4 v1 = *(const float4*)(p + (size_t)(slice * CPR + i + 1) * HW);
        s0.x += v0.x * v0.x; s0.y += v0.y * v0.y;
        s0.z += v0.z * v0.z; s0.w += v0.w * v0.w;
        s1.x += v1.x * v1.x; s1.y += v1.y * v1.y;
        s1.z += v1.z * v1.z; s1.w += v1.w * v1.w;
        vals[i]     = (short4v){ f2bf(v0.x), f2bf(v0.y), f2bf(v0.z), f2bf(v0.w) };
        vals[i + 1] = (short4v){ f2bf(v1.x), f2bf(v1.y), f2bf(v1.z), f2bf(v1.w) };
    }
    float4 s = { s0.x + s1.x, s0.y + s1.y, s0.z + s1.z, s0.w + s1.w };
    __shared__ float4 red[32][8];
    __shared__ float4 invl[8];
    red[slice][lanei] = s;
    __syncthreads();
    if (t < 8) {
        float4 tot = {0.f,0.f,0.f,0.f};
#pragma unroll
        for (int sl = 0; sl < 32; ++sl) {
            float4 v = red[sl][t];
            tot.x += v.x; tot.y += v.y; tot.z += v.z; tot.w += v.w;
        }
        invl[t] = (float4){ 1.f / (sqrtf(tot.x) + EPSF), 1.f / (sqrtf(tot.y) + EPSF),
                            1.f / (sqrtf(tot.z) + EPSF), 1.f / (sqrtf(tot.w) + EPSF) };
    }
    __syncthreads();
    const float4 iv = invl[lanei];
#pragma unroll
    for (int i = 0; i < CPR; ++i) {
        const int r = slice * CPR + i;
        short4v rv = vals[i];
        short4v o = { f2bf(bf2f(rv[0]) * iv.x), f2bf(bf2f(rv[1]) * iv.y),
                      f2bf(bf2f(rv[2]) * iv.z), f2bf(bf2f(rv[3]) * iv.w) };
        *(short4v*)(q + (size_t)r * HW) = o;
    }
}

__global__ __launch_bounds__(256) void prep_kernel(
    const float* __restrict__ x1t, const float* __restrict__ x1s,
    const float* __restrict__ x2t, const float* __restrict__ x2s,
    short* __restrict__ F, float* __restrict__ out)
{
    const int gp = blockIdx.x * 32;
    const int t = threadIdx.x;
    const int lanei = t & 7;
    if (blockIdx.x == 0 && t < 4) out[t] = 0.f;   // replaces memset dispatch
    if (gp < 16384)
        prep_body<128, 4096>(x1t, F + F1T, gp + lanei * 4, t);
    else if (gp < 32768)
        prep_body<128, 4096>(x1s, F + F1S, gp - 16384 + lanei * 4, t);
    else if (gp < 36864)
        prep_body<256, 1024>(x2t, F + F2T, gp - 32768 + lanei * 4, t);
    else
        prep_body<256, 1024>(x2s, F + F2S, gp - 36864 + lanei * 4, t);
}

// ------------- gram tile body: four quarter-bodies of 1 k-step -------------
// 8 loads in flight (~120 VGPR total) -> 4 waves/SIMD resident; four short
// latency exposures per wave, overlapped across 16 waves/CU.
template<int HW, bool SHARE>
__device__ inline void gram_body(const short* __restrict__ Fa,
                                 const short* __restrict__ Fb,
                                 int k0, int lane, float4v (&acc)[4][4])
{
    const int r16 = lane & 15, quad = lane >> 4;
    const int kb = k0 + quad * 8;
#pragma unroll 1
    for (int it = 0; it < 4; ++it) {
        short8v af[4], bfr[4];
#pragma unroll
        for (int rt = 0; rt < 4; ++rt)
            af[rt] = *(const short8v*)(
                Fa + (size_t)(rt * 16 + r16) * HW + kb + it * 32);
        if (!SHARE) {
#pragma unroll
            for (int ct = 0; ct < 4; ++ct)
                bfr[ct] = *(const short8v*)(
                    Fb + (size_t)(ct * 16 + r16) * HW + kb + it * 32);
        }
#pragma unroll
        for (int rt = 0; rt < 4; ++rt)
#pragma unroll
            for (int ct = 0; ct < 4; ++ct)
                acc[rt][ct] = __builtin_amdgcn_mfma_f32_16x16x32_bf16(
                    af[rt], SHARE ? af[ct] : bfr[ct], acc[rt][ct], 0, 0, 0);
    }
}

// ------------- stage A: 608 uniform blocks x 256 thr -----------------------
// Block = 64x64 tile x 512-px k-chunk (4 waves x 128 px). Combines its 4 wave
// partials in LDS, writes a LINEAR fp32 k-partial tile to ws (square deferred
// to stage B: sum over k must precede the square).
__global__ __launch_bounds__(256, 4) void gramA_kernel(
    const short* __restrict__ F, float* __restrict__ partials)
{
    __shared__ float buf[2][64 * 68];    // stride-68: 2-way bank alias (free)

    const int id = blockIdx.x;
    const int t = threadIdx.x, w = t >> 6, lane = t & 63;
    const int r16 = lane & 15, quad = lane >> 4;

    float4v acc[4][4];
#pragma unroll
    for (int i = 0; i < 4; ++i)
#pragma unroll
        for (int j = 0; j < 4; ++j) acc[i][j] = (float4v){0.f, 0.f, 0.f, 0.f};

    if (id < 320) {                      // group 1: c=128, hw=4096
        const int comb = id >> 5, sub = id & 31;
        const int b = sub >> 3, ks = sub & 7;
        const int g = g1_tab[comb][0];
        const int ra = g1_tab[comb][1] << 6, rb = g1_tab[comb][2] << 6;
        const short* Fa = (g == 1 ? F + F1S : F + F1T) + (size_t)(b * 128 + ra) * 4096;
        const short* Fb = (g == 0 ? F + F1T : F + F1S) + (size_t)(b * 128 + rb) * 4096;
        const int k0 = ks * 512 + w * 128;
        if (g < 2 && ra == rb) gram_body<4096, true >(Fa, Fa, k0, lane, acc);
        else                   gram_body<4096, false>(Fa, Fb, k0, lane, acc);
    } else {                             // group 2: c=256, hw=1024
        const int id2 = id - 320;
        const int comb = id2 >> 3, sub = id2 & 7;
        const int b = sub >> 1, ks = sub & 1;
        const int g = g2_tab[comb][0];
        const int ra = g2_tab[comb][1] << 6, rb = g2_tab[comb][2] << 6;
        const short* Fa = (g == 1 ? F + F2S : F + F2T) + (size_t)(b * 256 + ra) * 1024;
        const short* Fb = (g == 0 ? F + F2T : F + F2S) + (size_t)(b * 256 + rb) * 1024;
        const int k0 = ks * 512 + w * 128;
        if (g < 2 && ra == rb) gram_body<1024, true >(Fa, Fa, k0, lane, acc);
        else                   gram_body<1024, false>(Fa, Fb, k0, lane, acc);
    }

    // ---- combine 4 wave partials (2 rounds, 2 buffers) --------------------
    // C/D layout: col = lane&15, row = quad*4 + reg.
#pragma unroll 1
    for (int rr = 0; rr < 2; ++rr) {
        if ((w >> 1) == rr) {
            float* dst = buf[w & 1];
#pragma unroll
            for (int rt = 0; rt < 4; ++rt)
#pragma unroll
                for (int ct = 0; ct < 4; ++ct)
#pragma unroll
                    for (int r = 0; r < 4; ++r) {
                        int off = (rt * 16 + quad * 4 + r) * 68 + ct * 16 + r16;
                        if (rr == 0) dst[off] = acc[rt][ct][r];
                        else         dst[off] += acc[rt][ct][r];
                    }
        }
        __syncthreads();
    }
    // ---- write linear 64x64 fp32 k-partial (coalesced dwords) -------------
    float* dst = partials + (size_t)id * 4096;
#pragma unroll
    for (int i = 0; i < 16; ++i) {
        int cell = (i << 8) + t;         // lane-consecutive: coalesced store
        int off = (cell >> 6) * 68 + (cell & 63);   // conflict-free LDS read
        dst[cell] = buf[0][off] + buf[1][off];
    }
}

// ------------- stage B: 184 blocks; sum k-partials, square, weight ---------
template<int P>
__device__ inline float gramB_sum(const float* __restrict__ base, int t)
{
    float s = 0.f;
#pragma unroll
    for (int i = 0; i < 4; ++i) {
        const int c4 = i * 1024 + t * 4; // float4 lane-consecutive: coalesced
        float4 v = {0.f, 0.f, 0.f, 0.f};
#pragma unroll
        for (int p = 0; p < P; ++p) {
            float4 u = *(const float4*)(base + (size_t)p * 4096 + c4);
            v.x += u.x; v.y += u.y; v.z += u.z; v.w += u.w;
        }
        s += v.x * v.x + v.y * v.y + v.z * v.z + v.w * v.w;
    }
    return s;
}

__global__ __launch_bounds__(256) void gramB_kernel(
    const float* __restrict__ partials, float* __restrict__ out)
{
    __shared__ float scratch[256];
    const int tile = blockIdx.x, t = threadIdx.x;
    float s, wt; int which;
    if (tile < 40) {
        const int comb = tile >> 2, b = tile & 3;
        s = gramB_sum<8>(partials + (size_t)(comb * 32 + b * 8) * 4096, t);
        wt = (float)g1_tab[comb][3] * (1.0f / (4096.f * 4096.f * 4.f));
        which = 2;
    } else {
        const int t2 = tile - 40;
        const int comb = t2 >> 2, b = t2 & 3;
        s = gramB_sum<2>(partials + (size_t)(320 + comb * 8 + b * 2) * 4096, t);
        wt = (float)g2_tab[comb][3] * (1.0f / (1024.f * 1024.f * 4.f));
        which = 3;
    }
    s *= wt;
    scratch[t] = s;
    __syncthreads();
    for (int off = 128; off > 0; off >>= 1) {
        if (t < off) scratch[t] += scratch[t + off];
        __syncthreads();
    }
    if (t == 0) {
        float v = scratch[0];
        atomicAdd(&out[0], v);           // loss
        atomicAdd(&out[1], v);           // stack[0] = loss
        atomicAdd(&out[which], v);       // stack[1]=pwl_g1 / stack[2]=pwl_g2
    }
}

extern "C" void kernel_launch(void* const* d_in, const int* in_sizes, int n_in,
                              void* d_out, int out_size, void* d_ws, size_t ws_size,
                              hipStream_t stream)
{
    const float* x1t = (const float*)d_in[0];   // [4,128,64,64]
    const float* x1s = (const float*)d_in[1];
    const float* x2t = (const float*)d_in[2];   // [4,256,32,32]
    const float* x2s = (const float*)d_in[3];

    short* F        = (short*)d_ws;              // 6291456 shorts (12.6 MB)
    float* partials = (float*)d_ws + 3200000;    // 608 x 4096 floats (10 MB)

    prep_kernel<<<1280, 256, 0, stream>>>(x1t, x1s, x2t, x2s, F, (float*)d_out);
    gramA_kernel<<<608, 256, 0, stream>>>(F, partials);
    gramB_kernel<<<184, 256, 0, stream>>>(partials, (float*)d_out);
}